// Round 1
// baseline (553.505 us; speedup 1.0000x reference)
//
#include <hip/hip_runtime.h>
#include <hip/hip_bf16.h>
#include <cstdint>

#define ASPACE(n) __attribute__((address_space(n)))

typedef short bf16x8 __attribute__((ext_vector_type(8)));
typedef float f32x4 __attribute__((ext_vector_type(4)));

__device__ __forceinline__ unsigned short f2bf(float f) {
  uint32_t u = __float_as_uint(f);
  u += 0x7fffu + ((u >> 16) & 1u);
  return (unsigned short)(u >> 16);
}
__device__ __forceinline__ float bf2f(unsigned short h) {
  return __uint_as_float(((uint32_t)h) << 16);
}

// ---------------- fp32 -> bf16 conversion ----------------
__global__ __launch_bounds__(256) void conv_f32_bf16(const float4* __restrict__ src,
                                                     ushort4* __restrict__ dst, int n4) {
  int i = blockIdx.x * blockDim.x + threadIdx.x;
  int stride = gridDim.x * blockDim.x;
  for (; i < n4; i += stride) {
    float4 v = src[i];
    ushort4 o;
    o.x = f2bf(v.x); o.y = f2bf(v.y); o.z = f2bf(v.z); o.w = f2bf(v.w);
    dst[i] = o;
  }
}

// ---------------- bf16 GEMM (B^T input): C[m,n] = sum_k A[m,k]*B[n,k] ----------------
#define BM 128
#define BN 128
#define BKK 32

__device__ __forceinline__ void gload16(const unsigned short* g, unsigned short* l) {
  __builtin_amdgcn_global_load_lds((const ASPACE(1) void*)g, (ASPACE(3) void*)l, 16, 0, 0);
}

// OUT_MODE 0: bf16 out, no bias.  OUT_MODE 1: fp32 out + bias.
template <int OUT_MODE>
__global__ __launch_bounds__(256) void gemm_bt(const unsigned short* __restrict__ A,
                                               const unsigned short* __restrict__ B,
                                               void* __restrict__ Cout,
                                               const float* __restrict__ bias,
                                               int M, int N, int K) {
  __shared__ unsigned short As[BM * BKK];
  __shared__ unsigned short Bs[BN * BKK];
  const int tid  = threadIdx.x;
  const int lane = tid & 63;
  const int wave = tid >> 6;
  const int wr = wave >> 1, wc = wave & 1;
  const int bm0 = blockIdx.x * BM;
  const int bn0 = blockIdx.y * BN;

  f32x4 acc[4][4];
#pragma unroll
  for (int m = 0; m < 4; ++m)
#pragma unroll
    for (int n = 0; n < 4; ++n) {
      f32x4 z = {0.f, 0.f, 0.f, 0.f};
      acc[m][n] = z;
    }

  // staging: tile row-major [128][32] bf16 = 8 KiB = 8 wave-slots of 1024 B each.
  // slot s covers rows [s*16, s*16+16); lane covers row s*16 + lane/4, cols (lane%4)*8..+8
  const int srow = lane >> 2;
  const int scol = (lane & 3) * 8;
  const int s0 = wave * 2, s1 = wave * 2 + 1;

  const unsigned short* Abase = A + (size_t)bm0 * K;
  const unsigned short* Bbase = B + (size_t)bn0 * K;

  const int fr   = lane & 15;
  const int koff = (lane >> 4) * 8;

  for (int k0 = 0; k0 < K; k0 += BKK) {
    gload16(Abase + (size_t)(s0 * 16 + srow) * K + k0 + scol, As + s0 * 512);
    gload16(Abase + (size_t)(s1 * 16 + srow) * K + k0 + scol, As + s1 * 512);
    gload16(Bbase + (size_t)(s0 * 16 + srow) * K + k0 + scol, Bs + s0 * 512);
    gload16(Bbase + (size_t)(s1 * 16 + srow) * K + k0 + scol, Bs + s1 * 512);
    __syncthreads();  // drains vmcnt before barrier (compiler-inserted)

    bf16x8 af[4], bfv[4];
#pragma unroll
    for (int m = 0; m < 4; ++m)
      af[m] = *(const bf16x8*)(As + (wr * 64 + m * 16 + fr) * BKK + koff);
#pragma unroll
    for (int n = 0; n < 4; ++n)
      bfv[n] = *(const bf16x8*)(Bs + (wc * 64 + n * 16 + fr) * BKK + koff);
#pragma unroll
    for (int m = 0; m < 4; ++m)
#pragma unroll
      for (int n = 0; n < 4; ++n)
        acc[m][n] = __builtin_amdgcn_mfma_f32_16x16x32_bf16(af[m], bfv[n], acc[m][n], 0, 0, 0);
    __syncthreads();
  }

  // epilogue: C/D layout col = lane&15, row = (lane>>4)*4 + reg   [guide-verified m89/m91]
  const int rq = (lane >> 4) * 4;
  if (OUT_MODE == 1) {
    float* C = (float*)Cout;
#pragma unroll
    for (int m = 0; m < 4; ++m) {
#pragma unroll
      for (int n = 0; n < 4; ++n) {
        int col = bn0 + wc * 64 + n * 16 + fr;
        float bv = bias[col];
#pragma unroll
        for (int r = 0; r < 4; ++r) {
          int row = bm0 + wr * 64 + m * 16 + rq + r;
          C[(size_t)row * N + col] = acc[m][n][r] + bv;
        }
      }
    }
  } else {
    unsigned short* C = (unsigned short*)Cout;
#pragma unroll
    for (int m = 0; m < 4; ++m) {
#pragma unroll
      for (int n = 0; n < 4; ++n) {
        int col = bn0 + wc * 64 + n * 16 + fr;
#pragma unroll
        for (int r = 0; r < 4; ++r) {
          int row = bm0 + wr * 64 + m * 16 + rq + r;
          C[(size_t)row * N + col] = f2bf(acc[m][n][r]);
        }
      }
    }
  }
}

// ---------------- windowed attention ----------------
// qkv: bf16 [B*N, 1152] rows = tokens, cols = [q(0..383) | k(384..767) | v(768..1151)],
//      within each: head h occupies h*48..h*48+48
// aout: bf16 [B*N, 384], col = h*48 + d
__global__ __launch_bounds__(256) void win_attn(const unsigned short* __restrict__ qkv,
                                                unsigned short* __restrict__ aout) {
  const int blk = blockIdx.x;          // ((b*8 + h)*1024 + w)
  const int w = blk & 1023;
  const int h = (blk >> 10) & 7;
  const int b = blk >> 13;
  const int wy = w >> 5, wx = w & 31;

  __shared__ float q[16][48], k[16][48], v[16][48], P[16][16];
  const int tid = threadIdx.x;

  for (int idx = tid; idx < 768; idx += 256) {
    int t = idx / 48, d = idx - t * 48;
    int n = (wy * 4 + (t >> 2)) * 128 + wx * 4 + (t & 3);
    size_t base = ((size_t)(b * 16384 + n)) * 1152 + h * 48 + d;
    q[t][d] = bf2f(qkv[base]);
    k[t][d] = bf2f(qkv[base + 384]);
    v[t][d] = bf2f(qkv[base + 768]);
  }
  __syncthreads();

  const float scale = 0.14433756729740643f;  // 1/sqrt(48)
  {
    const int qi = tid >> 4, ki = tid & 15;
    float s = 0.f;
#pragma unroll
    for (int d = 0; d < 48; ++d) s += q[qi][d] * k[ki][d];
    s *= scale;
    // row-reduce over 16-lane groups (xor<16 stays within group)
    float mx = s;
    mx = fmaxf(mx, __shfl_xor(mx, 1));
    mx = fmaxf(mx, __shfl_xor(mx, 2));
    mx = fmaxf(mx, __shfl_xor(mx, 4));
    mx = fmaxf(mx, __shfl_xor(mx, 8));
    float p = __expf(s - mx);
    float sum = p;
    sum += __shfl_xor(sum, 1);
    sum += __shfl_xor(sum, 2);
    sum += __shfl_xor(sum, 4);
    sum += __shfl_xor(sum, 8);
    P[qi][ki] = p / sum;
  }
  __syncthreads();

  for (int idx = tid; idx < 768; idx += 256) {
    int qi = idx / 48, d = idx - qi * 48;
    float o = 0.f;
#pragma unroll
    for (int ki = 0; ki < 16; ++ki) o += P[qi][ki] * v[ki][d];
    int n = (wy * 4 + (qi >> 2)) * 128 + wx * 4 + (qi & 3);
    aout[((size_t)(b * 16384 + n)) * 384 + h * 48 + d] = f2bf(o);
  }
}

// ---------------- launch ----------------
extern "C" void kernel_launch(void* const* d_in, const int* in_sizes, int n_in,
                              void* d_out, int out_size, void* d_ws, size_t ws_size,
                              hipStream_t stream) {
  const float* x      = (const float*)d_in[0];
  const float* W_qkv  = (const float*)d_in[1];
  const float* W_proj = (const float*)d_in[2];
  const float* b_proj = (const float*)d_in[3];
  float* out = (float*)d_out;

  const int Bb = 8, Nn = 16384, Cc = 384;
  const int M = Bb * Nn;       // 131072
  const int threeC = 3 * Cc;   // 1152

  char* ws = (char*)d_ws;
  unsigned short* qkv_bf  = (unsigned short*)ws;                                   // M*1152 bf16
  unsigned short* xa_bf   = (unsigned short*)(ws + (size_t)M * threeC * 2);        // M*384  bf16 (x, then attn-out)
  unsigned short* wqkv_bf = (unsigned short*)(ws + (size_t)M * threeC * 2 + (size_t)M * Cc * 2);
  unsigned short* wproj_bf = wqkv_bf + threeC * Cc;

  // fp32 -> bf16
  conv_f32_bf16<<<2048, 256, 0, stream>>>((const float4*)x, (ushort4*)xa_bf, M * Cc / 4);
  conv_f32_bf16<<<432, 256, 0, stream>>>((const float4*)W_qkv, (ushort4*)wqkv_bf, threeC * Cc / 4);
  conv_f32_bf16<<<144, 256, 0, stream>>>((const float4*)W_proj, (ushort4*)wproj_bf, Cc * Cc / 4);

  // qkv = x @ W_qkv^T   (bf16 out)
  dim3 g1(M / BM, threeC / BN);
  gemm_bt<0><<<g1, 256, 0, stream>>>(xa_bf, wqkv_bf, qkv_bf, nullptr, M, threeC, Cc);

  // windowed attention -> xa_bf (x_bf16 no longer needed; stream-ordered reuse)
  win_attn<<<Bb * 8 * 1024, 256, 0, stream>>>(qkv_bf, xa_bf);

  // out = attn @ W_proj^T + b   (fp32 out)
  dim3 g2(M / BM, Cc / BN);
  gemm_bt<1><<<g2, 256, 0, stream>>>(xa_bf, wproj_bf, out, b_proj, M, Cc, Cc);
}

// Round 2
// 430.580 us; speedup vs baseline: 1.2855x; 1.2855x over previous
//
#include <hip/hip_runtime.h>
#include <hip/hip_bf16.h>
#include <cstdint>

#define ASPACE(n) __attribute__((address_space(n)))

typedef short bf16x8 __attribute__((ext_vector_type(8)));
typedef float f32x4 __attribute__((ext_vector_type(4)));

__device__ __forceinline__ unsigned short f2bf(float f) {
  uint32_t u = __float_as_uint(f);
  u += 0x7fffu + ((u >> 16) & 1u);
  return (unsigned short)(u >> 16);
}
__device__ __forceinline__ float bf2f(unsigned short h) {
  return __uint_as_float(((uint32_t)h) << 16);
}

// ---------------- fp32 -> bf16 conversion ----------------
__global__ __launch_bounds__(256) void conv_f32_bf16(const float4* __restrict__ src,
                                                     ushort4* __restrict__ dst, int n4) {
  int i = blockIdx.x * blockDim.x + threadIdx.x;
  int stride = gridDim.x * blockDim.x;
  for (; i < n4; i += stride) {
    float4 v = src[i];
    ushort4 o;
    o.x = f2bf(v.x); o.y = f2bf(v.y); o.z = f2bf(v.z); o.w = f2bf(v.w);
    dst[i] = o;
  }
}

// ---------------- bf16 GEMM (B^T input): C[m,n] = sum_k A[m,k]*B[n,k] ----------------
#define BM 128
#define BN 128
#define BKK 32

__device__ __forceinline__ void gload16(const unsigned short* g, unsigned short* l) {
  __builtin_amdgcn_global_load_lds((const ASPACE(1) void*)g, (ASPACE(3) void*)l, 16, 0, 0);
}

// OUT_MODE 0: bf16 out, no bias.  OUT_MODE 1: fp32 out + bias.
template <int OUT_MODE>
__global__ __launch_bounds__(256) void gemm_bt(const unsigned short* __restrict__ A,
                                               const unsigned short* __restrict__ B,
                                               void* __restrict__ Cout,
                                               const float* __restrict__ bias,
                                               int M, int N, int K) {
  __shared__ unsigned short As[BM * BKK];
  __shared__ unsigned short Bs[BN * BKK];
  const int tid  = threadIdx.x;
  const int lane = tid & 63;
  const int wave = tid >> 6;
  const int wr = wave >> 1, wc = wave & 1;
  const int bm0 = blockIdx.x * BM;
  const int bn0 = blockIdx.y * BN;

  f32x4 acc[4][4];
#pragma unroll
  for (int m = 0; m < 4; ++m)
#pragma unroll
    for (int n = 0; n < 4; ++n) {
      f32x4 z = {0.f, 0.f, 0.f, 0.f};
      acc[m][n] = z;
    }

  const int srow = lane >> 2;
  const int scol = (lane & 3) * 8;
  const int s0 = wave * 2, s1 = wave * 2 + 1;

  const unsigned short* Abase = A + (size_t)bm0 * K;
  const unsigned short* Bbase = B + (size_t)bn0 * K;

  const int fr   = lane & 15;
  const int koff = (lane >> 4) * 8;

  for (int k0 = 0; k0 < K; k0 += BKK) {
    gload16(Abase + (size_t)(s0 * 16 + srow) * K + k0 + scol, As + s0 * 512);
    gload16(Abase + (size_t)(s1 * 16 + srow) * K + k0 + scol, As + s1 * 512);
    gload16(Bbase + (size_t)(s0 * 16 + srow) * K + k0 + scol, Bs + s0 * 512);
    gload16(Bbase + (size_t)(s1 * 16 + srow) * K + k0 + scol, Bs + s1 * 512);
    __syncthreads();

    bf16x8 af[4], bfv[4];
#pragma unroll
    for (int m = 0; m < 4; ++m)
      af[m] = *(const bf16x8*)(As + (wr * 64 + m * 16 + fr) * BKK + koff);
#pragma unroll
    for (int n = 0; n < 4; ++n)
      bfv[n] = *(const bf16x8*)(Bs + (wc * 64 + n * 16 + fr) * BKK + koff);
#pragma unroll
    for (int m = 0; m < 4; ++m)
#pragma unroll
      for (int n = 0; n < 4; ++n)
        acc[m][n] = __builtin_amdgcn_mfma_f32_16x16x32_bf16(af[m], bfv[n], acc[m][n], 0, 0, 0);
    __syncthreads();
  }

  const int rq = (lane >> 4) * 4;
  if (OUT_MODE == 1) {
    float* C = (float*)Cout;
#pragma unroll
    for (int m = 0; m < 4; ++m) {
#pragma unroll
      for (int n = 0; n < 4; ++n) {
        int col = bn0 + wc * 64 + n * 16 + fr;
        float bv = bias[col];
#pragma unroll
        for (int r = 0; r < 4; ++r) {
          int row = bm0 + wr * 64 + m * 16 + rq + r;
          C[(size_t)row * N + col] = acc[m][n][r] + bv;
        }
      }
    }
  } else {
    unsigned short* C = (unsigned short*)Cout;
#pragma unroll
    for (int m = 0; m < 4; ++m) {
#pragma unroll
      for (int n = 0; n < 4; ++n) {
        int col = bn0 + wc * 64 + n * 16 + fr;
#pragma unroll
        for (int r = 0; r < 4; ++r) {
          int row = bm0 + wr * 64 + m * 16 + rq + r;
          C[(size_t)row * N + col] = f2bf(acc[m][n][r]);
        }
      }
    }
  }
}

// ---------------- windowed attention (MFMA, one wave per (b,h,window)) ----------------
// qkv: bf16 [B*N, 1152]; head h: q at h*48, k at 384+h*48, v at 768+h*48
// aout: bf16 [B*N, 384]
#define PADV 24
#define PADP 24
__global__ __launch_bounds__(256) void win_attn(const unsigned short* __restrict__ qkv,
                                                unsigned short* __restrict__ aout) {
  // per-wave LDS: Vt[48][PADV] + P[16][PADP]
  __shared__ unsigned short lds[4][48 * PADV + 16 * PADP];
  const int tid = threadIdx.x;
  const int wave = tid >> 6, lane = tid & 63;
  const int wg = blockIdx.x * 4 + wave;     // ((b*1024 + w)*8 + h)
  const int h = wg & 7;
  const int bw = wg >> 3;
  const int w = bw & 1023, b = bw >> 10;
  const int wy = w >> 5, wx = w & 31;

  unsigned short* Vt = lds[wave];
  unsigned short* P  = lds[wave] + 48 * PADV;

  const int lg = lane >> 4;   // 16-lane group 0..3
  const int lr = lane & 15;

  // token index in [0,16384) for window-row t (t = i*4+j -> n = (wy*4+i)*128 + wx*4+j)
  const int n_lr = (wy * 4 + (lr >> 2)) * 128 + wx * 4 + (lr & 3);
  const size_t rowbase = ((size_t)(b * 16384 + n_lr)) * 1152 + h * 48;

  // --- Q,K fragments direct from global (A/B frag: row = lane&15, k = (lane>>4)*8 + j) ---
  bf16x8 aq0, bk0;
  bf16x8 aq1 = {0, 0, 0, 0, 0, 0, 0, 0};
  bf16x8 bk1 = {0, 0, 0, 0, 0, 0, 0, 0};
  aq0 = *(const bf16x8*)(qkv + rowbase + lg * 8);
  bk0 = *(const bf16x8*)(qkv + rowbase + 384 + lg * 8);
  if (lg < 2) {
    aq1 = *(const bf16x8*)(qkv + rowbase + 32 + lg * 8);
    bk1 = *(const bf16x8*)(qkv + rowbase + 384 + 32 + lg * 8);
  }

  // --- stage V transposed into LDS: Vt[d][t] ---
  {
    bf16x8 v = *(const bf16x8*)(qkv + rowbase + 768 + lg * 8);   // part lg, token lr
#pragma unroll
    for (int i = 0; i < 8; ++i) Vt[(lg * 8 + i) * PADV + lr] = (unsigned short)v[i];
    if (lane < 32) {
      bf16x8 v2 = *(const bf16x8*)(qkv + rowbase + 768 + 32 + lg * 8);  // part 4+lg
#pragma unroll
      for (int i = 0; i < 8; ++i) Vt[((4 + lg) * 8 + i) * PADV + lr] = (unsigned short)v2[i];
    }
  }

  // --- S = Q K^T (two MFMAs: k=0..31 and k=32..63 with zero-pad past 48) ---
  f32x4 s = {0.f, 0.f, 0.f, 0.f};
  s = __builtin_amdgcn_mfma_f32_16x16x32_bf16(aq0, bk0, s, 0, 0, 0);
  s = __builtin_amdgcn_mfma_f32_16x16x32_bf16(aq1, bk1, s, 0, 0, 0);

  // --- softmax per row (C layout: row = lg*4 + r, col = lr); reduce over 16-lane group ---
  const float scale = 0.14433756729740643f;  // 1/sqrt(48)
  float p[4];
#pragma unroll
  for (int r = 0; r < 4; ++r) {
    float x = s[r] * scale;
    float m = x;
    m = fmaxf(m, __shfl_xor(m, 1));
    m = fmaxf(m, __shfl_xor(m, 2));
    m = fmaxf(m, __shfl_xor(m, 4));
    m = fmaxf(m, __shfl_xor(m, 8));
    float e = __expf(x - m);
    float t = e;
    t += __shfl_xor(t, 1);
    t += __shfl_xor(t, 2);
    t += __shfl_xor(t, 4);
    t += __shfl_xor(t, 8);
    p[r] = e / t;
  }
  // write P (bf16) to LDS: P[row][col]
#pragma unroll
  for (int r = 0; r < 4; ++r) P[(lg * 4 + r) * PADP + lr] = f2bf(p[r]);

  __syncthreads();  // order LDS writes (Vt, P) before fragment reads

  // --- O = P V  (3 MFMAs, one per 16-wide d chunk; k=16..31 zero-padded) ---
  bf16x8 ap = {0, 0, 0, 0, 0, 0, 0, 0};
  if (lg < 2) ap = *(const bf16x8*)(P + lr * PADP + lg * 8);

  f32x4 o[3];
#pragma unroll
  for (int c = 0; c < 3; ++c) {
    bf16x8 bv = {0, 0, 0, 0, 0, 0, 0, 0};
    if (lg < 2) bv = *(const bf16x8*)(Vt + (c * 16 + lr) * PADV + lg * 8);
    f32x4 z = {0.f, 0.f, 0.f, 0.f};
    o[c] = __builtin_amdgcn_mfma_f32_16x16x32_bf16(ap, bv, z, 0, 0, 0);
  }

  // --- store O: row qi = lg*4 + r, col = c*16 + lr ---
#pragma unroll
  for (int r = 0; r < 4; ++r) {
    const int qi = lg * 4 + r;
    const int nq = (wy * 4 + (qi >> 2)) * 128 + wx * 4 + (qi & 3);
    const size_t obase = ((size_t)(b * 16384 + nq)) * 384 + h * 48;
#pragma unroll
    for (int c = 0; c < 3; ++c)
      aout[obase + c * 16 + lr] = f2bf(o[c][r]);
  }
}

// ---------------- launch ----------------
extern "C" void kernel_launch(void* const* d_in, const int* in_sizes, int n_in,
                              void* d_out, int out_size, void* d_ws, size_t ws_size,
                              hipStream_t stream) {
  const float* x      = (const float*)d_in[0];
  const float* W_qkv  = (const float*)d_in[1];
  const float* W_proj = (const float*)d_in[2];
  const float* b_proj = (const float*)d_in[3];
  float* out = (float*)d_out;

  const int Bb = 8, Nn = 16384, Cc = 384;
  const int M = Bb * Nn;       // 131072
  const int threeC = 3 * Cc;   // 1152

  char* ws = (char*)d_ws;
  unsigned short* qkv_bf  = (unsigned short*)ws;                                   // M*1152 bf16
  unsigned short* xa_bf   = (unsigned short*)(ws + (size_t)M * threeC * 2);        // M*384  bf16
  unsigned short* wqkv_bf = (unsigned short*)(ws + (size_t)M * threeC * 2 + (size_t)M * Cc * 2);
  unsigned short* wproj_bf = wqkv_bf + threeC * Cc;

  conv_f32_bf16<<<2048, 256, 0, stream>>>((const float4*)x, (ushort4*)xa_bf, M * Cc / 4);
  conv_f32_bf16<<<432, 256, 0, stream>>>((const float4*)W_qkv, (ushort4*)wqkv_bf, threeC * Cc / 4);
  conv_f32_bf16<<<144, 256, 0, stream>>>((const float4*)W_proj, (ushort4*)wproj_bf, Cc * Cc / 4);

  dim3 g1(M / BM, threeC / BN);
  gemm_bt<0><<<g1, 256, 0, stream>>>(xa_bf, wqkv_bf, qkv_bf, nullptr, M, threeC, Cc);

  win_attn<<<Bb * 8 * 1024 / 4, 256, 0, stream>>>(qkv_bf, xa_bf);

  dim3 g2(M / BM, Cc / BN);
  gemm_bt<1><<<g2, 256, 0, stream>>>(xa_bf, wproj_bf, out, b_proj, M, Cc, Cc);
}